// Round 1
// baseline (4320.786 us; speedup 1.0000x reference)
//
#include <hip/hip_runtime.h>

// StyleLayer: modulated conv3x3 (demod folded into input/output scales) +
// fused polyphase upfirdn(up2) -> lrelu/clamp -> upfirdn(down2).
// Shapes: B=8, CIN=COUT=SDIM=512, H=W=64, K=3, taps=12, out 64x64.

#define B_    8
#define CIN_  512
#define COUT_ 512
#define SDIM_ 512
#define H_    64
#define W_    64
#define HO_   66      // conv output spatial (64 + 2*2 - 3 + 1)

// ---------------- s[b,c] = w @ (aw/sqrt(SDIM)).T + ab ----------------
__global__ void k_style_s(const float* __restrict__ w, const float* __restrict__ aw,
                          const float* __restrict__ ab, float* __restrict__ s) {
    int t = blockIdx.x * blockDim.x + threadIdx.x;    // 4096 = b*512+c
    int b = t >> 9, c = t & 511;
    const float inv = 0.044194173824159216f;          // 1/sqrt(512)
    const float* wp = w + b * SDIM_;
    const float* ap = aw + c * SDIM_;
    float acc = 0.f;
    for (int k = 0; k < SDIM_; ++k) acc += wp[k] * ap[k];
    s[t] = acc * inv + ab[c];
}

// ---------------- r[o,c] = sum_k cw[o,c,k]^2 ----------------
__global__ void k_style_r(const float* __restrict__ cw, float* __restrict__ r) {
    int t = blockIdx.x * blockDim.x + threadIdx.x;    // 262144 = o*512+c
    const float* p = cw + t * 9;
    float a = 0.f;
    #pragma unroll
    for (int k = 0; k < 9; ++k) a += p[k] * p[k];
    r[t] = a;
}

// ---------------- coef[b,o] = scale * d[b,o] * rsqrt(ema) ----------------
__global__ void k_style_coef(const float* __restrict__ s, const float* __restrict__ r,
                             const float* __restrict__ ema, float* __restrict__ coef) {
    int t = blockIdx.x * blockDim.x + threadIdx.x;    // 4096 = b*512+o
    int b = t >> 9, o = t & 511;
    const float scale2 = 1.0f / 4608.0f;              // (1/sqrt(CIN*K*K))^2
    const float* sp = s + b * 512;
    const float* rp = r + o * 512;
    float acc = 0.f;
    for (int c = 0; c < 512; ++c) { float sv = sp[c]; acc += sv * sv * rp[c]; }
    float d  = rsqrtf(scale2 * acc + 1e-8f);
    float ig = rsqrtf(ema[0]);
    coef[t] = d * ig * 0.014731391274719739f;         // * 1/sqrt(4608)
}

// ---------------- main conv: y1[b,o,66,66] ----------------
// tile: 22(w) x 11(h) outputs, 16 output channels per block.
__global__ __launch_bounds__(256) void k_style_conv(
    const float* __restrict__ x, const float* __restrict__ s,
    const float* __restrict__ cw, const float* __restrict__ coef,
    const float* __restrict__ bias, float* __restrict__ y1)
{
    __shared__ float xt[13][24];
    const int b   = blockIdx.z;
    const int o0  = blockIdx.y * 16;
    const int t   = blockIdx.x;          // 18 tiles: 3 in x, 6 in y
    const int tx0 = (t % 3) * 22;
    const int ty0 = (t / 3) * 11;
    const int tid = threadIdx.x;
    const int lx  = tid % 22, ly = tid / 22;
    const bool active = tid < 242;

    float acc[16];
    #pragma unroll
    for (int i = 0; i < 16; ++i) acc[i] = 0.f;

    const float* xb = x + (size_t)b * CIN_ * H_ * W_;
    const float* sb = s + b * CIN_;

    for (int c = 0; c < CIN_; ++c) {
        const float sc = sb[c];
        const float* xc = xb + (size_t)c * H_ * W_;
        for (int i = tid; i < 13 * 24; i += 256) {
            int rr = i / 24, cc = i % 24;
            int gy = ty0 - 2 + rr, gx = tx0 - 2 + cc;
            float v = 0.f;
            if (gy >= 0 && gy < H_ && gx >= 0 && gx < W_) v = xc[gy * W_ + gx] * sc;
            xt[rr][cc] = v;
        }
        __syncthreads();
        if (active) {
            float xv[9];
            #pragma unroll
            for (int ki = 0; ki < 3; ++ki)
                #pragma unroll
                for (int kj = 0; kj < 3; ++kj)
                    xv[ki * 3 + kj] = xt[ly + ki][lx + kj];
            const float* wc = cw + ((size_t)o0 * CIN_ + c) * 9;
            #pragma unroll
            for (int oo = 0; oo < 16; ++oo) {
                const float* wp = wc + (size_t)oo * CIN_ * 9;  // wave-uniform -> s_load
                #pragma unroll
                for (int k = 0; k < 9; ++k) acc[oo] += wp[k] * xv[k];
            }
        }
        __syncthreads();
    }
    if (active) {
        const int gy = ty0 + ly, gx = tx0 + lx;
        float* yb = y1 + ((size_t)(b * COUT_ + o0)) * HO_ * HO_ + gy * HO_ + gx;
        #pragma unroll
        for (int oo = 0; oo < 16; ++oo)
            yb[(size_t)oo * HO_ * HO_] = acc[oo] * coef[b * COUT_ + o0 + oo] + bias[o0 + oo];
    }
}

// ---------------- fused upfirdn2(up2,pad(9,8)) -> lrelu*sqrt2,clamp -> upfirdn2(down2) ----------------
// Per block: one (b,o) image, one 16x16 output tile.
// up polyphase (tap j even):  up[j] = 2*sum_q f[2q]  * I[j/2+1-q]
//             (tap j odd):    up[j] = 2*sum_q f[2q+1]* I[(j+1)/2-q]
// down: out[oy,ox] = sum_{v,u} f[11-v] f[11-u] z[2oy+v, 2ox+u]
__global__ __launch_bounds__(256) void k_style_fir(
    const float* __restrict__ y1, const float* __restrict__ uf,
    const float* __restrict__ df, float* __restrict__ out)
{
    __shared__ float It[26][27];
    __shared__ float hu[26][43];
    __shared__ float zt[42][43];
    __shared__ float dh[42][17];
    const int img = blockIdx.z;          // b*COUT + o
    const int oy0 = blockIdx.y * 16;
    const int ox0 = blockIdx.x * 16;
    const int tid = threadIdx.x;
    const float* I = y1 + (size_t)img * HO_ * HO_;

    // y1 tile rows/cols [oy0-4, oy0+21]
    for (int i = tid; i < 26 * 26; i += 256) {
        int rr = i / 26, cc = i % 26;
        int gy = oy0 - 4 + rr, gx = ox0 - 4 + cc;
        float v = 0.f;
        if (gy >= 0 && gy < HO_ && gx >= 0 && gx < HO_) v = I[gy * HO_ + gx];
        It[rr][cc] = v;
    }
    __syncthreads();

    // horizontal up-filter: hu[m][r], r -> up col 2*ox0+r
    for (int i = tid; i < 26 * 42; i += 256) {
        int m = i / 42, rr = i % 42;
        float a = 0.f;
        if ((rr & 1) == 0) {
            int base = rr / 2 + 5;
            #pragma unroll
            for (int q = 0; q < 6; ++q) a += uf[2 * q] * It[m][base - q];
        } else {
            int base = (rr + 1) / 2 + 4;
            #pragma unroll
            for (int q = 0; q < 6; ++q) a += uf[2 * q + 1] * It[m][base - q];
        }
        hu[m][rr] = 2.f * a;
    }
    __syncthreads();

    // vertical up-filter + lrelu*sqrt2 + clamp -> z
    for (int i = tid; i < 42 * 42; i += 256) {
        int ry = i / 42, rx = i % 42;
        float a = 0.f;
        if ((ry & 1) == 0) {
            int base = ry / 2 + 5;
            #pragma unroll
            for (int q = 0; q < 6; ++q) a += uf[2 * q] * hu[base - q][rx];
        } else {
            int base = (ry + 1) / 2 + 4;
            #pragma unroll
            for (int q = 0; q < 6; ++q) a += uf[2 * q + 1] * hu[base - q][rx];
        }
        a *= 2.f;
        a = (a >= 0.f ? a : a * 0.2f) * 1.4142135623730951f;
        a = fminf(fmaxf(a, -256.f), 256.f);
        zt[ry][rx] = a;
    }
    __syncthreads();

    // down horizontal (+decimate x)
    for (int i = tid; i < 42 * 16; i += 256) {
        int ry = i / 16, oxl = i % 16;
        float a = 0.f;
        #pragma unroll
        for (int u = 0; u < 12; ++u) a += zt[ry][2 * oxl + u] * df[11 - u];
        dh[ry][oxl] = a;
    }
    __syncthreads();

    // down vertical (+decimate y) + store
    {
        int oyl = tid / 16, oxl = tid % 16;
        float a = 0.f;
        #pragma unroll
        for (int v = 0; v < 12; ++v) a += dh[2 * oyl + v][oxl] * df[11 - v];
        out[(size_t)img * 64 * 64 + (oy0 + oyl) * 64 + (ox0 + oxl)] = a;
    }
}

extern "C" void kernel_launch(void* const* d_in, const int* in_sizes, int n_in,
                              void* d_out, int out_size, void* d_ws, size_t ws_size,
                              hipStream_t stream) {
    const float* x    = (const float*)d_in[0];
    const float* w    = (const float*)d_in[1];
    const float* aw   = (const float*)d_in[2];
    const float* ab   = (const float*)d_in[3];
    const float* cw   = (const float*)d_in[4];
    const float* bias = (const float*)d_in[5];
    const float* uf   = (const float*)d_in[6];
    const float* df   = (const float*)d_in[7];
    const float* ema  = (const float*)d_in[8];
    float* out = (float*)d_out;

    float* ws   = (float*)d_ws;
    float* s_   = ws;                       // 4096
    float* coef = ws + 4096;                // 4096
    float* r_   = ws + 8192;                // 262144
    float* y1   = ws + 8192 + 262144;       // 8*512*66*66 = 17,842,176

    k_style_s   <<<16,   256, 0, stream>>>(w, aw, ab, s_);
    k_style_r   <<<1024, 256, 0, stream>>>(cw, r_);
    k_style_coef<<<16,   256, 0, stream>>>(s_, r_, ema, coef);
    k_style_conv<<<dim3(18, 32, 8),   256, 0, stream>>>(x, s_, cw, coef, bias, y1);
    k_style_fir <<<dim3(4, 4, 4096),  256, 0, stream>>>(y1, uf, df, out);
}

// Round 2
// 622.213 us; speedup vs baseline: 6.9442x; 6.9442x over previous
//
#include <hip/hip_runtime.h>
#include <hip/hip_bf16.h>

// StyleLayer: modulated conv3x3 as bf16 MFMA implicit GEMM (demod folded into
// input/output scales) + fused polyphase upfirdn(up2)->lrelu/clamp->upfirdn(down2).
// B=8, CIN=COUT=SDIM=512, H=W=64, K=3, taps=12, out 64x64. Conv out 66x66 (=4356 px).

#define B_    8
#define CIN_  512
#define COUT_ 512
#define SDIM_ 512
#define H_    64
#define W_    64
#define HO_   66
#define NPIX  4356          // 66*66
#define XP    68            // padded input spatial (origin shift 2)

typedef short s8v  __attribute__((ext_vector_type(8)));   // 8 bf16 in 4 VGPRs
typedef float f4v  __attribute__((ext_vector_type(4)));

// ---------------- s[b,c] = w @ (aw/sqrt(SDIM)).T + ab ----------------
__global__ void k_style_s(const float* __restrict__ w, const float* __restrict__ aw,
                          const float* __restrict__ ab, float* __restrict__ s) {
    int t = blockIdx.x * blockDim.x + threadIdx.x;    // 4096 = b*512+c
    int b = t >> 9, c = t & 511;
    const float inv = 0.044194173824159216f;          // 1/sqrt(512)
    const float* wp = w + b * SDIM_;
    const float* ap = aw + c * SDIM_;
    float acc = 0.f;
    for (int k = 0; k < SDIM_; ++k) acc += wp[k] * ap[k];
    s[t] = acc * inv + ab[c];
}

// ---------------- r[o,c] = sum_k cw[o,c,k]^2 ----------------
__global__ void k_style_r(const float* __restrict__ cw, float* __restrict__ r) {
    int t = blockIdx.x * blockDim.x + threadIdx.x;    // 262144 = o*512+c
    const float* p = cw + t * 9;
    float a = 0.f;
    #pragma unroll
    for (int k = 0; k < 9; ++k) a += p[k] * p[k];
    r[t] = a;
}

// ---------------- coef[b,o] = scale * d[b,o] * rsqrt(ema) ----------------
__global__ void k_style_coef(const float* __restrict__ s, const float* __restrict__ r,
                             const float* __restrict__ ema, float* __restrict__ coef) {
    int t = blockIdx.x * blockDim.x + threadIdx.x;    // 4096 = b*512+o
    int b = t >> 9, o = t & 511;
    const float scale2 = 1.0f / 4608.0f;
    const float* sp = s + b * 512;
    const float* rp = r + o * 512;
    float acc = 0.f;
    for (int c = 0; c < 512; ++c) { float sv = sp[c]; acc += sv * sv * rp[c]; }
    float d  = rsqrtf(scale2 * acc + 1e-8f);
    float ig = rsqrtf(ema[0]);
    coef[t] = d * ig * 0.014731391274719739f;         // * 1/sqrt(4608)
}

// ---------------- wb[tap][o][c] = bf16(cw[o][c][tap]) ----------------
__global__ __launch_bounds__(256) void k_prep_w(const float* __restrict__ cw,
                                                __hip_bfloat16* __restrict__ wb) {
    int t = blockIdx.x * 256 + threadIdx.x;           // 9*512*512 = 2359296
    int tap = t / (512 * 512);
    int rem = t - tap * 512 * 512;
    int o = rem >> 9, c = rem & 511;
    wb[t] = __float2bfloat16(cw[(o * 512 + c) * 9 + tap]);
}

// ---------------- xt[b][y][x][c] = bf16(x[b][c][y-2][x-2] * s[b][c]), zero pad ----
// block = (y, b); LDS-transpose per 64-channel chunk.
__global__ __launch_bounds__(256) void k_prep_x(const float* __restrict__ x,
                                                const float* __restrict__ s,
                                                __hip_bfloat16* __restrict__ xt) {
    __shared__ float tile[64][65];
    const int y = blockIdx.x;            // 0..67
    const int b = blockIdx.y;
    const int tid = threadIdx.x;
    const bool yin = (y >= 2 && y < 66);
    __hip_bfloat16* orow = xt + ((size_t)(b * XP + y)) * XP * 512;
    for (int c0 = 0; c0 < 512; c0 += 64) {
        if (yin) {
            for (int i = tid; i < 64 * 64; i += 256) {
                int c = i >> 6, xx = i & 63;
                tile[c][xx] = x[(((size_t)b * 512 + c0 + c) * 64 + (y - 2)) * 64 + xx]
                              * s[b * 512 + c0 + c];
            }
        }
        __syncthreads();
        for (int j = tid; j < 68 * 8; j += 256) {     // 68 x-positions, 8 c-groups of 8
            int xx = j >> 3, cg = j & 7;
            bool xin = yin && (xx >= 2 && xx < 66);
            union { ushort u[8]; float4 f4; } pk;
            #pragma unroll
            for (int k = 0; k < 8; ++k) {
                float v = xin ? tile[cg * 8 + k][xx - 2] : 0.f;
                __hip_bfloat16 h = __float2bfloat16(v);
                pk.u[k] = *reinterpret_cast<ushort*>(&h);
            }
            *reinterpret_cast<float4*>(orow + (size_t)xx * 512 + c0 + cg * 8) = pk.f4;
        }
        __syncthreads();
    }
}

// ---------------- MFMA implicit-GEMM conv ----------------
// Per block: 128 o x 128 px tile for one batch. K = 9 taps x 512 c, BK=32.
// LDS [row][32c] per operand; 16B slot swizzle: slot' = slot ^ ((row>>1)&3).
__device__ __forceinline__ void gload16(const void* g, void* l) {
    __builtin_amdgcn_global_load_lds(
        (const __attribute__((address_space(1))) unsigned*)g,
        (__attribute__((address_space(3))) unsigned*)l, 16, 0, 0);
}

__device__ __forceinline__ void conv_stage(
    const __hip_bfloat16* __restrict__ wb, const __hip_bfloat16* __restrict__ xt,
    __hip_bfloat16* lA, __hip_bfloat16* lB,
    int b, int o0, int p0, int st, int wv, int ln)
{
    const int tap = st >> 4;
    const int cc  = (st & 15) << 5;
    const int ki = tap / 3, kj = tap - ki * 3;
    #pragma unroll
    for (int i = 0; i < 2; ++i) {                      // A: 512 chunks of 16B
        int j = i * 256 + wv * 64 + ln;
        int o = j >> 2, sl = j & 3;
        const __hip_bfloat16* src = wb + (((size_t)tap * 512 + o0 + o) * 512 + cc
                                          + ((sl ^ ((o >> 1) & 3)) << 3));
        gload16(src, lA + (size_t)(i * 256 + wv * 64) * 8);
    }
    const size_t bbase = (size_t)b * XP * XP * 512;
    #pragma unroll
    for (int i = 0; i < 2; ++i) {                      // B: 512 chunks of 16B
        int j = i * 256 + wv * 64 + ln;
        int pix = j >> 2, sl = j & 3;
        int p = p0 + pix; p = p < (NPIX - 1) ? p : (NPIX - 1);
        int py = (int)(((unsigned)p * 63551u) >> 22);  // p/66, valid p<67650
        int px = p - py * 66;
        const __hip_bfloat16* src = xt + (bbase + (size_t)((py + ki) * XP + (px + kj)) * 512
                                          + cc + ((sl ^ ((pix >> 1) & 3)) << 3));
        gload16(src, lB + (size_t)(i * 256 + wv * 64) * 8);
    }
}

__global__ __launch_bounds__(256) void k_conv_mfma(
    const __hip_bfloat16* __restrict__ wb, const __hip_bfloat16* __restrict__ xt,
    const float* __restrict__ coef, const float* __restrict__ bias,
    __hip_bfloat16* __restrict__ y1)
{
    __shared__ __hip_bfloat16 ldsA[2][128][32];
    __shared__ __hip_bfloat16 ldsB[2][128][32];
    const int b  = blockIdx.z;
    const int o0 = blockIdx.y * 128;
    const int p0 = blockIdx.x * 128;
    const int tid = threadIdx.x, wv = tid >> 6, ln = tid & 63;
    const int wm = wv >> 1, wn = wv & 1;               // wave -> 64x64 quadrant

    f4v acc[4][4];
    #pragma unroll
    for (int fm = 0; fm < 4; ++fm)
        #pragma unroll
        for (int fn = 0; fn < 4; ++fn) acc[fm][fn] = (f4v){0.f, 0.f, 0.f, 0.f};

    conv_stage(wb, xt, &ldsA[0][0][0], &ldsB[0][0][0], b, o0, p0, 0, wv, ln);
    __syncthreads();                                   // drains vmcnt (compiler)

    for (int st = 0; st < 144; ++st) {
        const int cur = st & 1;
        if (st != 143)
            conv_stage(wb, xt, &ldsA[cur ^ 1][0][0], &ldsB[cur ^ 1][0][0],
                       b, o0, p0, st + 1, wv, ln);
        const __hip_bfloat16* A  = &ldsA[cur][0][0];
        const __hip_bfloat16* Bm = &ldsB[cur][0][0];
        s8v af[4], bfr[4];
        #pragma unroll
        for (int f = 0; f < 4; ++f) {
            int r  = wm * 64 + f * 16 + (ln & 15);
            int sa = (ln >> 4) ^ ((r >> 1) & 3);
            af[f] = *reinterpret_cast<const s8v*>(A + (size_t)r * 32 + sa * 8);
            int rb = wn * 64 + f * 16 + (ln & 15);
            int sb = (ln >> 4) ^ ((rb >> 1) & 3);
            bfr[f] = *reinterpret_cast<const s8v*>(Bm + (size_t)rb * 32 + sb * 8);
        }
        #pragma unroll
        for (int fm = 0; fm < 4; ++fm)
            #pragma unroll
            for (int fn = 0; fn < 4; ++fn)
                acc[fm][fn] = __builtin_amdgcn_mfma_f32_16x16x32_bf16(
                    af[fm], bfr[fn], acc[fm][fn], 0, 0, 0);
        __syncthreads();                               // single barrier per step
    }

    // epilogue: y1[b][o][p] bf16 = acc*coef + bias
    #pragma unroll
    for (int fm = 0; fm < 4; ++fm) {
        #pragma unroll
        for (int fn = 0; fn < 4; ++fn) {
            int p = p0 + wn * 64 + fn * 16 + (ln & 15);
            if (p < NPIX) {
                int ob = o0 + wm * 64 + fm * 16 + (ln >> 4) * 4;
                #pragma unroll
                for (int j = 0; j < 4; ++j) {
                    int o = ob + j;
                    float v = acc[fm][fn][j] * coef[b * 512 + o] + bias[o];
                    y1[((size_t)(b * 512 + o)) * NPIX + p] = __float2bfloat16(v);
                }
            }
        }
    }
}

// ---------------- fused upfirdn2(up2,pad(9,8)) -> lrelu*sqrt2,clamp -> upfirdn2(down2) ----
__global__ __launch_bounds__(256) void k_style_fir(
    const __hip_bfloat16* __restrict__ y1, const float* __restrict__ uf,
    const float* __restrict__ df, float* __restrict__ out)
{
    __shared__ float It[26][27];
    __shared__ float hu[26][43];
    __shared__ float zt[42][43];
    __shared__ float dh[42][17];
    const int img = blockIdx.z;          // b*COUT + o
    const int oy0 = blockIdx.y * 16;
    const int ox0 = blockIdx.x * 16;
    const int tid = threadIdx.x;
    const __hip_bfloat16* I = y1 + (size_t)img * NPIX;

    for (int i = tid; i < 26 * 26; i += 256) {
        int rr = i / 26, cc = i % 26;
        int gy = oy0 - 4 + rr, gx = ox0 - 4 + cc;
        float v = 0.f;
        if (gy >= 0 && gy < HO_ && gx >= 0 && gx < HO_) v = __bfloat162float(I[gy * HO_ + gx]);
        It[rr][cc] = v;
    }
    __syncthreads();

    for (int i = tid; i < 26 * 42; i += 256) {
        int m = i / 42, rr = i % 42;
        float a = 0.f;
        if ((rr & 1) == 0) {
            int base = rr / 2 + 5;
            #pragma unroll
            for (int q = 0; q < 6; ++q) a += uf[2 * q] * It[m][base - q];
        } else {
            int base = (rr + 1) / 2 + 4;
            #pragma unroll
            for (int q = 0; q < 6; ++q) a += uf[2 * q + 1] * It[m][base - q];
        }
        hu[m][rr] = 2.f * a;
    }
    __syncthreads();

    for (int i = tid; i < 42 * 42; i += 256) {
        int ry = i / 42, rx = i % 42;
        float a = 0.f;
        if ((ry & 1) == 0) {
            int base = ry / 2 + 5;
            #pragma unroll
            for (int q = 0; q < 6; ++q) a += uf[2 * q] * hu[base - q][rx];
        } else {
            int base = (ry + 1) / 2 + 4;
            #pragma unroll
            for (int q = 0; q < 6; ++q) a += uf[2 * q + 1] * hu[base - q][rx];
        }
        a *= 2.f;
        a = (a >= 0.f ? a : a * 0.2f) * 1.4142135623730951f;
        a = fminf(fmaxf(a, -256.f), 256.f);
        zt[ry][rx] = a;
    }
    __syncthreads();

    for (int i = tid; i < 42 * 16; i += 256) {
        int ry = i / 16, oxl = i % 16;
        float a = 0.f;
        #pragma unroll
        for (int u = 0; u < 12; ++u) a += zt[ry][2 * oxl + u] * df[11 - u];
        dh[ry][oxl] = a;
    }
    __syncthreads();

    {
        int oyl = tid / 16, oxl = tid % 16;
        float a = 0.f;
        #pragma unroll
        for (int v = 0; v < 12; ++v) a += dh[2 * oyl + v][oxl] * df[11 - v];
        out[(size_t)img * 64 * 64 + (oy0 + oyl) * 64 + (ox0 + oxl)] = a;
    }
}

extern "C" void kernel_launch(void* const* d_in, const int* in_sizes, int n_in,
                              void* d_out, int out_size, void* d_ws, size_t ws_size,
                              hipStream_t stream) {
    const float* x    = (const float*)d_in[0];
    const float* w    = (const float*)d_in[1];
    const float* aw   = (const float*)d_in[2];
    const float* ab   = (const float*)d_in[3];
    const float* cw   = (const float*)d_in[4];
    const float* bias = (const float*)d_in[5];
    const float* uf   = (const float*)d_in[6];
    const float* df   = (const float*)d_in[7];
    const float* ema  = (const float*)d_in[8];
    float* out = (float*)d_out;

    float* ws   = (float*)d_ws;
    float* s_   = ws;                                   // 4096
    float* coef = ws + 4096;                            // 4096
    float* r_   = ws + 8192;                            // 262144
    // bf16 regions (sizes in float-slots): y1 8,921,088 | xt 9,469,952 | wb 1,179,648
    __hip_bfloat16* y1 = (__hip_bfloat16*)(ws + 270336);
    __hip_bfloat16* xt = (__hip_bfloat16*)(ws + 270336 + 8921088);
    __hip_bfloat16* wb = (__hip_bfloat16*)(ws + 270336 + 8921088 + 9469952);

    k_style_s   <<<16,   256, 0, stream>>>(w, aw, ab, s_);
    k_style_r   <<<1024, 256, 0, stream>>>(cw, r_);
    k_style_coef<<<16,   256, 0, stream>>>(s_, r_, ema, coef);
    k_prep_w    <<<9216, 256, 0, stream>>>(cw, wb);
    k_prep_x    <<<dim3(68, 8), 256, 0, stream>>>(x, s_, xt);
    k_conv_mfma <<<dim3(35, 4, 8), 256, 0, stream>>>(wb, xt, coef, bias, y1);
    k_style_fir <<<dim3(4, 4, 4096), 256, 0, stream>>>(y1, uf, df, out);
}